// Round 3
// baseline (1784.300 us; speedup 1.0000x reference)
//
#include <hip/hip_runtime.h>

// bf16 MFMA fragment types per cdna_hip_programming.md §3
typedef short short8 __attribute__((ext_vector_type(8)));   // 8 bf16 (4 VGPRs)
typedef float f32x4 __attribute__((ext_vector_type(4)));    // 4 fp32 acc
typedef unsigned int uint4v __attribute__((ext_vector_type(4)));

static constexpr int kH = 128;   // hidden dim

// fp32 -> bf16 round-to-nearest-even, manual (no HIP class types: bit_cast-safe)
__device__ __forceinline__ unsigned f2bf(float f) {
    unsigned u = __builtin_bit_cast(unsigned, f);
    u += 0x7fffu + ((u >> 16) & 1u);
    return u >> 16;
}
__device__ __forceinline__ unsigned pack_bf16x2(float a, float b) {
    return f2bf(a) | (f2bf(b) << 16);   // a = element 0 (low 16)
}

struct U128 { unsigned x, y, z, w; };

// ---------- table fp32 -> bf16 conversion (streaming, BW-bound) ----------
__global__ void cvt_bf16(const float* __restrict__ src, unsigned* __restrict__ dst, long n4) {
    long i = (long)blockIdx.x * blockDim.x + threadIdx.x;   // 4 floats per thread
    if (i < n4) {
        float4 f = ((const float4*)src)[i];
        ((uint2*)dst)[i] = make_uint2(pack_bf16x2(f.x, f.y), pack_bf16x2(f.z, f.w));
    }
}

// ---------- shared W1->LDS fill (B-fragment order) ----------
// short index ((s*8+nt)*64 + lane)*8 + j  = B[n = nt*16+(lane&15)][k = s*32+(lane>>4)*8+j]
template <int BLK>
__device__ __forceinline__ void fill_w1(const float* __restrict__ W1, unsigned* ldsB, int tid) {
    #pragma unroll 4
    for (int i = 0; i < 16384 / BLK; ++i) {
        int lin2 = tid + i * BLK;          // uint index
        int j  = (lin2 & 3) * 2;
        int l  = (lin2 >> 2) & 63;
        int nt = (lin2 >> 8) & 7;
        int s  = (lin2 >> 11) & 7;
        int q = l >> 4, n = l & 15;
        int k = s * 32 + q * 8 + j;
        int ncol = nt * 16 + n;
        ldsB[lin2] = pack_bf16x2(W1[k * kH + ncol], W1[(k + 1) * kH + ncol]);
    }
}

// ---------- epilogue: h = relu(acc+b1); out = h.W2 + b2 ----------
// C layout: col = lane&15 (output n), row = q*4 + reg (edge within M-tile)
__device__ __forceinline__ void epilogue(
    const f32x4 acc[2][8], const float b1v[8], const float w2v[8], float b2s,
    float* __restrict__ out, int ebase, int E, int q, int n16)
{
    #pragma unroll
    for (int mt = 0; mt < 2; ++mt) {
        float p[4];
        #pragma unroll
        for (int r = 0; r < 4; ++r) {
            float sum = 0.f;
            #pragma unroll
            for (int nt = 0; nt < 8; ++nt)
                sum += fmaxf(acc[mt][nt][r] + b1v[nt], 0.f) * w2v[nt];
            sum += __shfl_xor(sum, 1);
            sum += __shfl_xor(sum, 2);
            sum += __shfl_xor(sum, 4);
            sum += __shfl_xor(sum, 8);
            p[r] = sum + b2s;
        }
        if (n16 == 0) {
            int eb = ebase + mt * 16 + q * 4;
            if (eb + 3 < E) {
                *(float4*)(out + eb) = make_float4(p[0], p[1], p[2], p[3]);
            } else {
                #pragma unroll
                for (int r = 0; r < 4; ++r)
                    if (eb + r < E) out[eb + r] = p[r];
            }
        }
    }
}

// ---------- bf16-table gather+MLP: block = 512 thr (8 waves), 2 blocks/CU = 16 waves/CU ----------
__global__ __launch_bounds__(512, 4) void edge_mlp_bf16(
    const unsigned short* __restrict__ zc, const unsigned short* __restrict__ za,
    const int* __restrict__ row, const int* __restrict__ col,
    const float* __restrict__ W1, const float* __restrict__ b1,
    const float* __restrict__ W2, const float* __restrict__ b2,
    float* __restrict__ out, int E, int ntiles)
{
    __shared__ unsigned ldsB[16384];  // 64 KiB, W1 bf16 fragment-ordered
    const int tid = threadIdx.x;
    fill_w1<512>(W1, ldsB, tid);
    __syncthreads();

    const int w   = tid >> 6;   // wave 0..7
    const int l   = tid & 63;
    const int q   = l >> 4;
    const int n16 = l & 15;

    float b1v[8], w2v[8];
    #pragma unroll
    for (int nt = 0; nt < 8; ++nt) {
        b1v[nt] = b1[nt * 16 + n16];
        w2v[nt] = W2[nt * 16 + n16];
    }
    const float b2s = b2[0];

    for (int tile = blockIdx.x; tile < ntiles; tile += gridDim.x) {
        const int ebase = tile * 256 + w * 32;   // 32 edges/wave, 256/block
        int ce0 = min(ebase + n16, E - 1);
        int ce1 = min(ebase + 16 + n16, E - 1);
        const unsigned short* pc0 = zc + (size_t)row[ce0] * kH;
        const unsigned short* pa0 = za + (size_t)col[ce0] * kH;
        const unsigned short* pc1 = zc + (size_t)row[ce1] * kH;
        const unsigned short* pa1 = za + (size_t)col[ce1] * kH;

        f32x4 acc[2][8];
        #pragma unroll
        for (int mt = 0; mt < 2; ++mt)
            #pragma unroll
            for (int nt = 0; nt < 8; ++nt)
                acc[mt][nt] = f32x4{0.f, 0.f, 0.f, 0.f};

        #pragma unroll
        for (int s = 0; s < 8; ++s) {
            // k = s*32 + q*8 + (0..7): one 16-B bf16 load per edge-slot, no repack
            const unsigned short* s0 = (s < 4) ? (pc0 + s * 32) : (pa0 + (s - 4) * 32);
            const unsigned short* s1 = (s < 4) ? (pc1 + s * 32) : (pa1 + (s - 4) * 32);
            short8 a0 = *(const short8*)(s0 + q * 8);
            short8 a1 = *(const short8*)(s1 + q * 8);
            #pragma unroll
            for (int nt = 0; nt < 8; ++nt) {
                uint4v bu = *(const uint4v*)(&ldsB[((s * 8 + nt) * 64 + l) * 4]);
                short8 bv = __builtin_bit_cast(short8, bu);
                acc[0][nt] = __builtin_amdgcn_mfma_f32_16x16x32_bf16(a0, bv, acc[0][nt], 0, 0, 0);
                acc[1][nt] = __builtin_amdgcn_mfma_f32_16x16x32_bf16(a1, bv, acc[1][nt], 0, 0, 0);
            }
        }
        epilogue(acc, b1v, w2v, b2s, out, ebase, E, q, n16);
    }
}

// ---------- fp32-table fallback (ws too small): same structure, packs on the fly ----------
__global__ __launch_bounds__(512, 4) void edge_mlp_f32(
    const float* __restrict__ zc, const float* __restrict__ za,
    const int* __restrict__ row, const int* __restrict__ col,
    const float* __restrict__ W1, const float* __restrict__ b1,
    const float* __restrict__ W2, const float* __restrict__ b2,
    float* __restrict__ out, int E, int ntiles)
{
    __shared__ unsigned ldsB[16384];
    const int tid = threadIdx.x;
    fill_w1<512>(W1, ldsB, tid);
    __syncthreads();

    const int w   = tid >> 6;
    const int l   = tid & 63;
    const int q   = l >> 4;
    const int n16 = l & 15;

    float b1v[8], w2v[8];
    #pragma unroll
    for (int nt = 0; nt < 8; ++nt) {
        b1v[nt] = b1[nt * 16 + n16];
        w2v[nt] = W2[nt * 16 + n16];
    }
    const float b2s = b2[0];

    for (int tile = blockIdx.x; tile < ntiles; tile += gridDim.x) {
        const int ebase = tile * 256 + w * 32;
        int ce0 = min(ebase + n16, E - 1);
        int ce1 = min(ebase + 16 + n16, E - 1);
        const float* pc0 = zc + (size_t)row[ce0] * kH;
        const float* pa0 = za + (size_t)col[ce0] * kH;
        const float* pc1 = zc + (size_t)row[ce1] * kH;
        const float* pa1 = za + (size_t)col[ce1] * kH;

        f32x4 acc[2][8];
        #pragma unroll
        for (int mt = 0; mt < 2; ++mt)
            #pragma unroll
            for (int nt = 0; nt < 8; ++nt)
                acc[mt][nt] = f32x4{0.f, 0.f, 0.f, 0.f};

        #pragma unroll
        for (int s = 0; s < 8; ++s) {
            const float* s0 = (s < 4) ? (pc0 + s * 32) : (pa0 + (s - 4) * 32);
            const float* s1 = (s < 4) ? (pc1 + s * 32) : (pa1 + (s - 4) * 32);
            float4 fa = *(const float4*)(s0 + q * 8);
            float4 fb = *(const float4*)(s0 + q * 8 + 4);
            float4 fc = *(const float4*)(s1 + q * 8);
            float4 fd = *(const float4*)(s1 + q * 8 + 4);
            U128 ua{pack_bf16x2(fa.x, fa.y), pack_bf16x2(fa.z, fa.w),
                    pack_bf16x2(fb.x, fb.y), pack_bf16x2(fb.z, fb.w)};
            U128 ub{pack_bf16x2(fc.x, fc.y), pack_bf16x2(fc.z, fc.w),
                    pack_bf16x2(fd.x, fd.y), pack_bf16x2(fd.z, fd.w)};
            short8 a0 = __builtin_bit_cast(short8, ua);
            short8 a1 = __builtin_bit_cast(short8, ub);
            #pragma unroll
            for (int nt = 0; nt < 8; ++nt) {
                uint4v bu = *(const uint4v*)(&ldsB[((s * 8 + nt) * 64 + l) * 4]);
                short8 bv = __builtin_bit_cast(short8, bu);
                acc[0][nt] = __builtin_amdgcn_mfma_f32_16x16x32_bf16(a0, bv, acc[0][nt], 0, 0, 0);
                acc[1][nt] = __builtin_amdgcn_mfma_f32_16x16x32_bf16(a1, bv, acc[1][nt], 0, 0, 0);
            }
        }
        epilogue(acc, b1v, w2v, b2s, out, ebase, E, q, n16);
    }
}

extern "C" void kernel_launch(void* const* d_in, const int* in_sizes, int n_in,
                              void* d_out, int out_size, void* d_ws, size_t ws_size,
                              hipStream_t stream) {
    const float* zc = (const float*)d_in[0];   // [N_CUST, 128] fp32
    const float* za = (const float*)d_in[1];   // [N_ART, 128] fp32
    const int*   row = (const int*)d_in[2];
    const int*   col = (const int*)d_in[3];
    const float* W1 = (const float*)d_in[4];
    const float* b1 = (const float*)d_in[5];
    const float* W2 = (const float*)d_in[6];
    const float* b2 = (const float*)d_in[7];
    float* out = (float*)d_out;

    int E = in_sizes[2];
    long nc_elems = in_sizes[0];               // N_CUST*128
    long na_elems = in_sizes[1];               // N_ART*128
    size_t need = (size_t)(nc_elems + na_elems) * 2;   // bf16 tables

    int ntiles = (E + 255) / 256;              // 256 edges per 512-thread block
    int grid = ntiles < 512 ? ntiles : 512;    // 2 blocks/CU resident, persistent

    if (ws_size >= need) {
        unsigned short* wsC = (unsigned short*)d_ws;
        unsigned short* wsA = wsC + nc_elems;
        long c4 = nc_elems / 4, a4 = na_elems / 4;
        cvt_bf16<<<(int)((c4 + 255) / 256), 256, 0, stream>>>(zc, (unsigned*)wsC, c4);
        cvt_bf16<<<(int)((a4 + 255) / 256), 256, 0, stream>>>(za, (unsigned*)wsA, a4);
        edge_mlp_bf16<<<grid, 512, 0, stream>>>(wsC, wsA, row, col, W1, b1, W2, b2, out, E, ntiles);
    } else {
        edge_mlp_f32<<<grid, 512, 0, stream>>>(zc, za, row, col, W1, b1, W2, b2, out, E, ntiles);
    }
}